// Round 17
// baseline (88.254 us; speedup 1.0000x reference)
//
#include <hip/hip_runtime.h>
#include <hip/hip_bf16.h>
#include <math.h>

#define NPIX 4096   // H*W
#define CIN  512
#define DD   64
#define BB   4
#define NCHUNK 8    // KV chunks for flash-decode split (chunk = 512)

using f32x4  = __attribute__((ext_vector_type(4))) float;
using bf16x8 = __attribute__((ext_vector_type(8))) short;
using u16x4  = __attribute__((ext_vector_type(4))) unsigned short;
using u32x2  = __attribute__((ext_vector_type(2))) unsigned int;

__device__ __forceinline__ unsigned short f2bf(float f){
    union { __hip_bfloat16 h; unsigned short u; } v;
    v.h = __float2bfloat16(f);            // RNE
    return v.u;
}

__device__ __forceinline__ float bf2f(unsigned short u){
    union { unsigned u; float f; } v; v.u = ((unsigned)u) << 16; return v.f;
}

__device__ __forceinline__ unsigned pk2(float a, float b){
    union { __hip_bfloat162 h; unsigned u; } v;
    v.h = __float22bfloat162_rn(make_float2(a, b));   // v_cvt_pk_bf16_f32
    return v.u;
}

__device__ __forceinline__ bf16x8 cvt8(float4 a, float4 b){
    union { unsigned u[4]; bf16x8 v; } r;
    r.u[0] = pk2(a.x, a.y); r.u[1] = pk2(a.z, a.w);
    r.u[2] = pk2(b.x, b.y); r.u[3] = pk2(b.z, b.w);
    return r.v;
}

// async global->LDS DMA, 16 B per lane (dest = uniform base + lane*16)
__device__ __forceinline__ void gload_lds16(const void* g, void* l){
    __builtin_amdgcn_global_load_lds(
        (const __attribute__((address_space(1))) unsigned int*)g,
        (__attribute__((address_space(3))) unsigned int*)l, 16, 0, 0);
}

// ---------------------------------------------------------------------------
// Kernel 1: fused transpose + theta/phi/g 1x1 conv via MFMA.  [frozen r14]
// ---------------------------------------------------------------------------
__global__ __launch_bounds__(256, 4) void k1_qkv(
    const float* __restrict__ x,
    const float* __restrict__ tw, const float* __restrict__ tbv,
    const float* __restrict__ pw, const float* __restrict__ pbv,
    const float* __restrict__ gw, const float* __restrict__ gbv,
    unsigned short* __restrict__ thetaT, unsigned short* __restrict__ phiT,
    unsigned short* __restrict__ g_dn)
{
    const int n0 = blockIdx.x * 64;
    const int kt = blockIdx.y;
    const int b  = blockIdx.z;
    const int tid = threadIdx.x;
    const float* W  = (kt==0) ? tw  : (kt==1) ? pw  : gw;
    const float* Bv = (kt==0) ? tbv : (kt==1) ? pbv : gbv;
    const float wsc = (kt==0) ? 1.4426950408889634f : 1.0f;   // log2(e)

    const int wq   = tid >> 6;
    const int lane = tid & 63;
    const int lr   = lane & 15;
    const int lg   = lane >> 4;

    __shared__ __align__(16) unsigned short T[64*72];  // x tile [k][n] bf16
    __shared__ __align__(16) short Wt[64*72];          // W tile [m][k] bf16
    __shared__ __align__(16) short Xt[64*72];          // x tile [n][k] bf16

    f32x4 acc[4];
    #pragma unroll
    for (int jt=0;jt<4;++jt) acc[jt] = (f32x4){0.f,0.f,0.f,0.f};

    const int srow = tid >> 2;           // staging row 0..63
    const int skq  = (tid & 3) * 16;     // staging 16-seg

    for (int k0 = 0; k0 < CIN; k0 += 64) {
        __syncthreads();                 // protect T/Wt/Xt prev-iter reads
        {   // stage W [64 m][64 k] fp32 -> bf16 (scaled)
            const float* wp = W + (size_t)srow*CIN + k0 + skq;
            float4 w0 = *reinterpret_cast<const float4*>(wp);
            float4 w1 = *reinterpret_cast<const float4*>(wp + 4);
            float4 w2 = *reinterpret_cast<const float4*>(wp + 8);
            float4 w3 = *reinterpret_cast<const float4*>(wp + 12);
            w0.x*=wsc; w0.y*=wsc; w0.z*=wsc; w0.w*=wsc;
            w1.x*=wsc; w1.y*=wsc; w1.z*=wsc; w1.w*=wsc;
            w2.x*=wsc; w2.y*=wsc; w2.z*=wsc; w2.w*=wsc;
            w3.x*=wsc; w3.y*=wsc; w3.z*=wsc; w3.w*=wsc;
            *reinterpret_cast<bf16x8*>(&Wt[srow*72 + skq])     = cvt8(w0, w1);
            *reinterpret_cast<bf16x8*>(&Wt[srow*72 + skq + 8]) = cvt8(w2, w3);
            // stage x [64 k][64 n] fp32 coalesced -> T bf16 [k][n]
            const float* xp = x + ((size_t)b*CIN + k0 + srow)*NPIX + n0 + skq;
            float4 a0 = *reinterpret_cast<const float4*>(xp);
            float4 a1 = *reinterpret_cast<const float4*>(xp + 4);
            float4 a2 = *reinterpret_cast<const float4*>(xp + 8);
            float4 a3 = *reinterpret_cast<const float4*>(xp + 12);
            *reinterpret_cast<bf16x8*>(&T[srow*72 + skq])     = cvt8(a0, a1);
            *reinterpret_cast<bf16x8*>(&T[srow*72 + skq + 8]) = cvt8(a2, a3);
        }
        __syncthreads();
        {   // transpose T[k][n] -> Xt[n][k]
            unsigned short v[16];
            #pragma unroll
            for (int i=0;i<16;++i) v[i] = T[(skq+i)*72 + srow];
            *reinterpret_cast<bf16x8*>(&Xt[srow*72 + skq])     = *reinterpret_cast<bf16x8*>(&v[0]);
            *reinterpret_cast<bf16x8*>(&Xt[srow*72 + skq + 8]) = *reinterpret_cast<bf16x8*>(&v[8]);
        }
        __syncthreads();

        __builtin_amdgcn_s_setprio(1);
        #pragma unroll
        for (int dc=0;dc<2;++dc){
            bf16x8 af = *reinterpret_cast<const bf16x8*>(&Wt[(wq*16+lr)*72 + dc*32 + lg*8]);
            #pragma unroll
            for (int jt=0;jt<4;++jt){
                bf16x8 bf = *reinterpret_cast<const bf16x8*>(&Xt[(jt*16+lr)*72 + dc*32 + lg*8]);
                acc[jt] = __builtin_amdgcn_mfma_f32_16x16x32_bf16(af, bf, acc[jt], 0,0,0);
            }
        }
        __builtin_amdgcn_s_setprio(0);
    }

    // acc[jt][r] = out[m = wq*16+lg*4+r][n = n0+jt*16+lr]
    const int mb = wq*16 + lg*4;
    float bv[4];
    #pragma unroll
    for (int r=0;r<4;++r) bv[r] = Bv[mb+r] * wsc;

    if (kt < 2){
        unsigned short* dst = (kt==0) ? thetaT : phiT;   // [b][n][d], d contig
        #pragma unroll
        for (int jt=0;jt<4;++jt){
            union { unsigned u[2]; u16x4 v; } o;
            o.u[0] = pk2(acc[jt][0]+bv[0], acc[jt][1]+bv[1]);
            o.u[1] = pk2(acc[jt][2]+bv[2], acc[jt][3]+bv[3]);
            *reinterpret_cast<u16x4*>(&dst[((size_t)b*NPIX + n0 + jt*16+lr)*DD + mb]) = o.v;
        }
    } else {
        #pragma unroll
        for (int jt=0;jt<4;++jt)
            #pragma unroll
            for (int r=0;r<4;++r)
                g_dn[((size_t)b*DD + mb+r)*NPIX + n0 + jt*16+lr] = f2bf(acc[jt][r]+bv[r]);
    }
}

// ---------------------------------------------------------------------------
// Kernel 2: MFMA flash attention with 2-PHASE global_load_lds PIPELINE.
// Double-buffered LINEAR Kt/Gt (stride 64) with G4 XOR swizzle
// (byte ^= (row&7)<<4) applied on the per-lane GLOBAL source address and
// again on the ds_read side (rule 21: both-sides-or-neither).
// STAGE(next) issued at top of iter (HW DMA, no regs), compute current,
// ONE __syncthreads per tile (vmcnt drain lands post-compute -> hidden).
// Swapped QK^T, dual-strip P (pad-72, ds_write path), bf16 pY partials.
// grid (32 q-tiles, NCHUNK, 4 b), block 256 (4 waves).
// ---------------------------------------------------------------------------
__global__ __launch_bounds__(256, 4) void k2_attn(
    const unsigned short* __restrict__ thetaT,
    const unsigned short* __restrict__ phiT,
    const unsigned short* __restrict__ g_dn,
    unsigned short* __restrict__ pY, float* __restrict__ pL)
{
    const int i0 = blockIdx.x * 128;
    const int ch = blockIdx.y;
    const int b  = blockIdx.z;
    const int tid  = threadIdx.x;
    const int wq   = tid >> 6;        // wave 0..3
    const int lane = tid & 63;
    const int lr   = lane & 15;       // row/col-in-16
    const int lg   = lane >> 4;       // k-group 0..3

    __shared__ __align__(16) short Kt[2*64*64];    // dbuf phiT tile [j][d], linear
    __shared__ __align__(16) short Gt[2*64*64];    // dbuf g tile [d][j], linear
    __shared__ __align__(16) short Pb[4*32*72];    // per-wave P [2 strips x 16 q][j]
    short* Pw = &Pb[wq*32*72];
    char*  KtB = (char*)Kt;
    char*  GtB = (char*)Gt;

    const unsigned short* phb = phiT + (size_t)b*NPIX*DD;
    const unsigned short* gb  = g_dn + (size_t)b*DD*NPIX;

    // staging geometry: wave w stages 4KB (32 rows); waves 0-1 -> Kt, 2-3 -> Gt
    const int sseg  = wq & 1;             // row half 0/1
    const int lrow  = lane >> 3;          // 0..7  (== row % 8 for all 4 issues)
    const int lcolB = (lane & 7) << 4;    // byte col 0..112
    const int scolX = lcolB ^ (lrow << 4);// swizzled source byte col

    #define K2STAGE(BUF, J0) { \
        if (wq < 2){ \
            const char* gs = (const char*)phb + ((size_t)((J0) + sseg*32 + lrow))*128 + scolX; \
            char* ls = KtB + (BUF)*8192 + sseg*4096; \
            gload_lds16(gs,            ls); \
            gload_lds16(gs +  8*128,   ls + 1024); \
            gload_lds16(gs + 16*128,   ls + 2048); \
            gload_lds16(gs + 24*128,   ls + 3072); \
        } else { \
            const char* gs = (const char*)gb + ((size_t)(sseg*32 + lrow))*8192 + (size_t)(J0)*2 + scolX; \
            char* ls = GtB + (BUF)*8192 + sseg*4096; \
            gload_lds16(gs,             ls); \
            gload_lds16(gs +  8*8192,   ls + 1024); \
            gload_lds16(gs + 16*8192,   ls + 2048); \
            gload_lds16(gs + 24*8192,   ls + 3072); \
        } }

    // Q fragments, strip0: rows i0+wq*16+lr ; strip1: +64
    bf16x8 qf0[2], qf1[2];
    {
        const unsigned short* qp0 = thetaT + ((size_t)b*NPIX + i0 + wq*16 + lr)*DD + lg*8;
        qf0[0] = *reinterpret_cast<const bf16x8*>(qp0);
        qf0[1] = *reinterpret_cast<const bf16x8*>(qp0 + 32);
        const unsigned short* qp1 = qp0 + (size_t)64*DD;
        qf1[0] = *reinterpret_cast<const bf16x8*>(qp1);
        qf1[1] = *reinterpret_cast<const bf16x8*>(qp1 + 32);
    }
    const bf16x8 onesf = { (short)0x3F80,(short)0x3F80,(short)0x3F80,(short)0x3F80,
                           (short)0x3F80,(short)0x3F80,(short)0x3F80,(short)0x3F80 };

    f32x4 yacc0[4], yacc1[4], lacc0, lacc1;
    #pragma unroll
    for (int dt=0;dt<4;++dt){
        yacc0[dt] = (f32x4){0.f,0.f,0.f,0.f};
        yacc1[dt] = (f32x4){0.f,0.f,0.f,0.f};
    }
    lacc0 = (f32x4){0.f,0.f,0.f,0.f};
    lacc1 = (f32x4){0.f,0.f,0.f,0.f};

    const int jbeg = ch * (NPIX / NCHUNK);
    const int jend = jbeg + (NPIX / NCHUNK);
    const int swzK = (lr & 7) << 4;       // read-side XOR (row%8 == lr%8)

    K2STAGE(0, jbeg);
    __syncthreads();                      // drain prologue DMA

    int cur = 0;
    for (int j0 = jbeg; j0 < jend; j0 += 64) {
        const bool more = (j0 + 64 < jend);
        if (more) K2STAGE(cur^1, j0 + 64);   // DMA flies under compute

        const char* kc = KtB + cur*8192;
        const char* gc = GtB + cur*8192;

        // ---- S^T: mfma(A=K, B=Q).  Lane: q=lr (col), j = jt*16+lg*4+r ----
        f32x4 s0[4], s1[4];
        #pragma unroll
        for (int jt=0;jt<4;++jt){
            s0[jt] = (f32x4){0.f,0.f,0.f,0.f};
            s1[jt] = (f32x4){0.f,0.f,0.f,0.f};
        }
        __builtin_amdgcn_s_setprio(1);
        #pragma unroll
        for (int dc=0;dc<2;++dc){
            #pragma unroll
            for (int jt=0;jt<4;++jt){
                bf16x8 bf = *reinterpret_cast<const bf16x8*>(
                    kc + (jt*16+lr)*128 + ((dc*64 + lg*16) ^ swzK));
                s0[jt] = __builtin_amdgcn_mfma_f32_16x16x32_bf16(bf, qf0[dc], s0[jt], 0,0,0);
                s1[jt] = __builtin_amdgcn_mfma_f32_16x16x32_bf16(bf, qf1[dc], s1[jt], 0,0,0);
            }
        }
        __builtin_amdgcn_s_setprio(0);

        // ---- p = exp2(S^T) -> packed bf16, one b64 write per (jt,strip) ----
        #pragma unroll
        for (int jt=0;jt<4;++jt){
            u32x2 w0, w1;
            w0.x = pk2(exp2f(s0[jt][0]), exp2f(s0[jt][1]));
            w0.y = pk2(exp2f(s0[jt][2]), exp2f(s0[jt][3]));
            *reinterpret_cast<u32x2*>(&Pw[lr*72      + jt*16 + lg*4]) = w0;
            w1.x = pk2(exp2f(s1[jt][0]), exp2f(s1[jt][1]));
            w1.y = pk2(exp2f(s1[jt][2]), exp2f(s1[jt][3]));
            *reinterpret_cast<u32x2*>(&Pw[(16+lr)*72 + jt*16 + lg*4]) = w1;
        }
        // same-wave write->read: compiler inserts lgkmcnt waits

        // ---- PV: each Gt fragment feeds both strips ----
        __builtin_amdgcn_s_setprio(1);
        #pragma unroll
        for (int jc=0;jc<2;++jc){
            bf16x8 af0 = *reinterpret_cast<const bf16x8*>(&Pw[lr*72      + jc*32 + lg*8]);
            bf16x8 af1 = *reinterpret_cast<const bf16x8*>(&Pw[(16+lr)*72 + jc*32 + lg*8]);
            #pragma unroll
            for (int dt=0;dt<4;++dt){
                bf16x8 gf = *reinterpret_cast<const bf16x8*>(
                    gc + (dt*16+lr)*128 + ((jc*64 + lg*16) ^ swzK));
                yacc0[dt] = __builtin_amdgcn_mfma_f32_16x16x32_bf16(af0, gf, yacc0[dt], 0,0,0);
                yacc1[dt] = __builtin_amdgcn_mfma_f32_16x16x32_bf16(af1, gf, yacc1[dt], 0,0,0);
            }
            lacc0 = __builtin_amdgcn_mfma_f32_16x16x32_bf16(af0, onesf, lacc0, 0,0,0);
            lacc1 = __builtin_amdgcn_mfma_f32_16x16x32_bf16(af1, onesf, lacc1, 0,0,0);
        }
        __builtin_amdgcn_s_setprio(0);

        if (more){
            __syncthreads();              // drains next-tile DMA (post-compute)
            cur ^= 1;
        }
    }
    #undef K2STAGE

    // ---- epilogue: store UNNORMALIZED bf16 partials + l (both strips) ----
    {
        unsigned short* py0 = pY + (((size_t)b*NCHUNK + ch)*NPIX + i0 + wq*16)*DD;
        unsigned short* py1 = py0 + (size_t)64*DD;
        #pragma unroll
        for (int r=0;r<4;++r)
            #pragma unroll
            for (int dt=0;dt<4;++dt){
                py0[(size_t)(lg*4+r)*DD + dt*16 + lr] = f2bf(yacc0[dt][r]);
                py1[(size_t)(lg*4+r)*DD + dt*16 + lr] = f2bf(yacc1[dt][r]);
            }
        if (lr == 0){
            const size_t base = ((size_t)b*NCHUNK + ch)*NPIX + i0 + wq*16;
            #pragma unroll
            for (int r=0;r<4;++r){
                pL[base + lg*4+r]      = lacc0[r];
                pL[base + 64 + lg*4+r] = lacc1[r];
            }
        }
    }
}

// ---------------------------------------------------------------------------
// Kernel 3: FUSED combine + out conv via MFMA + BN partial stats. [r16]
// ---------------------------------------------------------------------------
__global__ __launch_bounds__(256) void k3_out(
    const unsigned short* __restrict__ pY, const float* __restrict__ pL,
    const float* __restrict__ ow, const float* __restrict__ ob,
    unsigned short* __restrict__ y2b,
    float* __restrict__ psum, float* __restrict__ qsum)
{
    const int n0 = blockIdx.x * 64;
    const int c0 = blockIdx.y * 64;
    const int b  = blockIdx.z;
    const int tid = threadIdx.x;
    const int wq   = tid >> 6;
    const int lane = tid & 63;
    const int lr   = lane & 15;
    const int lg   = lane >> 4;

    __shared__ __align__(16) short Ot[64*72];
    __shared__ __align__(16) short Yt[64*72];

    {   // stage ow [64 c][64 d] fp32 -> bf16
        const int srow = tid >> 2, skq = (tid & 3) * 16;
        const float* wp = ow + (size_t)(c0+srow)*DD + skq;
        float4 w0 = *reinterpret_cast<const float4*>(wp);
        float4 w1 = *reinterpret_cast<const float4*>(wp + 4);
        float4 w2 = *reinterpret_cast<const float4*>(wp + 8);
        float4 w3 = *reinterpret_cast<const float4*>(wp + 12);
        *reinterpret_cast<bf16x8*>(&Ot[srow*72 + skq])     = cvt8(w0, w1);
        *reinterpret_cast<bf16x8*>(&Ot[srow*72 + skq + 8]) = cvt8(w2, w3);

        // combine NCHUNK partials of yT[n=srow][d=skq..+15] in f32, normalize
        float ya[16];
        #pragma unroll
        for (int i=0;i<16;++i) ya[i] = 0.f;
        float lsum = 0.f;
        #pragma unroll
        for (int c=0;c<NCHUNK;++c){
            const unsigned short* yp =
                pY + (((size_t)b*NCHUNK + c)*NPIX + n0 + srow)*DD + skq;
            bf16x8 v0 = *reinterpret_cast<const bf16x8*>(yp);
            bf16x8 v1 = *reinterpret_cast<const bf16x8*>(yp + 8);
            #pragma unroll
            for (int i=0;i<8;++i){
                ya[i]   += bf2f((unsigned short)v0[i]);
                ya[8+i] += bf2f((unsigned short)v1[i]);
            }
            lsum += pL[((size_t)b*NCHUNK + c)*NPIX + n0 + srow];
        }
        const float inv = 1.f / lsum;
        union { unsigned u[8]; bf16x8 v[2]; } o;
        #pragma unroll
        for (int i=0;i<8;++i) o.u[i] = pk2(ya[2*i]*inv, ya[2*i+1]*inv);
        *reinterpret_cast<bf16x8*>(&Yt[srow*72 + skq])     = o.v[0];
        *reinterpret_cast<bf16x8*>(&Yt[srow*72 + skq + 8]) = o.v[1];
    }
    __syncthreads();

    f32x4 acc[4];
    #pragma unroll
    for (int jt=0;jt<4;++jt) acc[jt] = (f32x4){0.f,0.f,0.f,0.f};
    #pragma unroll
    for (int dc=0;dc<2;++dc){
        bf16x8 af = *reinterpret_cast<const bf16x8*>(&Ot[(wq*16+lr)*72 + dc*32 + lg*8]);
        #pragma unroll
        for (int jt=0;jt<4;++jt){
            bf16x8 bf = *reinterpret_cast<const bf16x8*>(&Yt[(jt*16+lr)*72 + dc*32 + lg*8]);
            acc[jt] = __builtin_amdgcn_mfma_f32_16x16x32_bf16(af, bf, acc[jt], 0,0,0);
        }
    }

    const int cb = c0 + wq*16 + lg*4;
    float bv[4];
    #pragma unroll
    for (int r=0;r<4;++r) bv[r] = ob[cb+r];

    float sr[4] = {0,0,0,0}, qr[4] = {0,0,0,0};
    #pragma unroll
    for (int jt=0;jt<4;++jt)
        #pragma unroll
        for (int r=0;r<4;++r){
            float v = acc[jt][r] + bv[r];
            y2b[((size_t)b*CIN + cb+r)*NPIX + n0 + jt*16+lr] = f2bf(v);
            sr[r] += v; qr[r] += v*v;
        }
    // reduce over lr (lane bits 0..3) -> per-channel partials for 64 n
    #pragma unroll
    for (int off=1; off<16; off<<=1)
        #pragma unroll
        for (int r=0;r<4;++r){
            sr[r] += __shfl_xor(sr[r], off);
            qr[r] += __shfl_xor(qr[r], off);
        }
    if (lr == 0){
        const int slot = b*64 + blockIdx.x;
        #pragma unroll
        for (int r=0;r<4;++r){
            psum[(size_t)(cb+r)*256 + slot] = sr[r];
            qsum[(size_t)(cb+r)*256 + slot] = qr[r];
        }
    }
}

// ---------------------------------------------------------------------------
// Kernel 3b: reduce [512][256] partials -> mean/inv (deterministic tree).
// ---------------------------------------------------------------------------
__global__ __launch_bounds__(256) void k3b_stats(
    const float* __restrict__ psum, const float* __restrict__ qsum,
    float* __restrict__ meanA, float* __restrict__ invA)
{
    const int c = blockIdx.x;
    const int tid = threadIdx.x;
    float s = psum[(size_t)c*256 + tid];
    float q = qsum[(size_t)c*256 + tid];
    __shared__ float rs[256], rq[256];
    rs[tid]=s; rq[tid]=q; __syncthreads();
    for (int off=128; off; off>>=1){
        if (tid<off){ rs[tid]+=rs[tid+off]; rq[tid]+=rq[tid+off]; }
        __syncthreads();
    }
    if (tid==0){
        const float n = (float)(BB*NPIX);
        float mm = rs[0] / n;
        float v = rq[0] / n - mm*mm;
        meanA[c]=mm; invA[c]=rsqrtf(v + 1e-5f);
    }
}

// ---------------------------------------------------------------------------
// Kernel 4: BN apply + residual.  Reads y2b (bf16, ws), writes out (f32).
// ---------------------------------------------------------------------------
__global__ __launch_bounds__(256) void k4_final(
    const float* __restrict__ x, const unsigned short* __restrict__ y2b,
    const float* __restrict__ meanA, const float* __restrict__ invA,
    const float* __restrict__ gamma, const float* __restrict__ beta,
    const float* __restrict__ scale, float* __restrict__ out)
{
    const float sc = scale[0];
    const int total4 = BB*CIN*NPIX/4;
    for (int i4 = blockIdx.x*blockDim.x + threadIdx.x; i4 < total4;
         i4 += gridDim.x*blockDim.x){
        int c = (i4 >> 10) & (CIN-1);
        float4 xv = reinterpret_cast<const float4*>(x)[i4];
        ushort4 yv = reinterpret_cast<const ushort4*>(y2b)[i4];
        float mm = meanA[c], iv = invA[c], g = gamma[c], bt = beta[c];
        float4 o;
        o.x = xv.x + sc*(g*(bf2f(yv.x)-mm)*iv + bt);
        o.y = xv.y + sc*(g*(bf2f(yv.y)-mm)*iv + bt);
        o.z = xv.z + sc*(g*(bf2f(yv.z)-mm)*iv + bt);
        o.w = xv.w + sc*(g*(bf2f(yv.w)-mm)*iv + bt);
        reinterpret_cast<float4*>(out)[i4] = o;
    }
}

// ---------------------------------------------------------------------------
extern "C" void kernel_launch(void* const* d_in, const int* in_sizes, int n_in,
                              void* d_out, int out_size, void* d_ws, size_t ws_size,
                              hipStream_t stream)
{
    const float* x     = (const float*)d_in[0];
    const float* tw    = (const float*)d_in[1];
    const float* tbv   = (const float*)d_in[2];
    const float* pw    = (const float*)d_in[3];
    const float* pbv   = (const float*)d_in[4];
    const float* gw    = (const float*)d_in[5];
    const float* gbv   = (const float*)d_in[6];
    const float* ow    = (const float*)d_in[7];
    const float* ob    = (const float*)d_in[8];
    const float* gamma = (const float*)d_in[9];
    const float* beta  = (const float*)d_in[10];
    const float* scale = (const float*)d_in[11];
    float* out = (float*)d_out;

    char* wsb = (char*)d_ws;
    unsigned short* thetaT = (unsigned short*)(wsb);             // 2 MB
    unsigned short* phiT   = (unsigned short*)(wsb + 2097152);   // 2 MB
    unsigned short* g_dn   = (unsigned short*)(wsb + 4194304);   // 2 MB
    float*          pL     = (float*)(wsb + 8388608);            // 512 KB
    float*          psum   = (float*)(wsb + 8912896);            // 512 KB
    float*          qsum   = (float*)(wsb + 9437184);            // 512 KB
    float*          meanA  = (float*)(wsb + 9961472);
    float*          invA   = (float*)(wsb + 9963520);
    unsigned short* y2b    = (unsigned short*)(wsb + 16777216);  // 16.8 MB

    // d_out (33.5 MB) time-shared scratch:
    //   phase B: pY [B][NCHUNK=8][N][D] bf16 (16.8 MB) -- k2 writes, k3 reads
    //   phase C: final output f32 -- k4 writes (every element)
    unsigned short* pY = (unsigned short*)d_out;

    k1_qkv <<<dim3(64,3,4), 256, 0, stream>>>(x, tw, tbv, pw, pbv, gw, gbv,
                                              thetaT, phiT, g_dn);
    k2_attn<<<dim3(32,NCHUNK,4), 256, 0, stream>>>(thetaT, phiT, g_dn, pY, pL);
    k3_out <<<dim3(64,8,4), 256, 0, stream>>>(pY, pL, ow, ob, y2b, psum, qsum);
    k3b_stats<<<512, 256, 0, stream>>>(psum, qsum, meanA, invA);
    k4_final<<<2048, 256, 0, stream>>>(x, y2b, meanA, invA, gamma, beta, scale, out);
}

// Round 18
// 84.611 us; speedup vs baseline: 1.0431x; 1.0431x over previous
//
#include <hip/hip_runtime.h>
#include <hip/hip_bf16.h>
#include <math.h>

#define NPIX 4096   // H*W
#define CIN  512
#define DD   64
#define BB   4
#define NCHUNK 8    // KV chunks for flash-decode split (chunk = 512)

using f32x4  = __attribute__((ext_vector_type(4))) float;
using bf16x8 = __attribute__((ext_vector_type(8))) short;
using u16x4  = __attribute__((ext_vector_type(4))) unsigned short;
using u32x2  = __attribute__((ext_vector_type(2))) unsigned int;

__device__ __forceinline__ unsigned short f2bf(float f){
    union { __hip_bfloat16 h; unsigned short u; } v;
    v.h = __float2bfloat16(f);            // RNE
    return v.u;
}

__device__ __forceinline__ float bf2f(unsigned short u){
    union { unsigned u; float f; } v; v.u = ((unsigned)u) << 16; return v.f;
}

__device__ __forceinline__ unsigned pk2(float a, float b){
    union { __hip_bfloat162 h; unsigned u; } v;
    v.h = __float22bfloat162_rn(make_float2(a, b));   // v_cvt_pk_bf16_f32
    return v.u;
}

__device__ __forceinline__ bf16x8 cvt8(float4 a, float4 b){
    union { unsigned u[4]; bf16x8 v; } r;
    r.u[0] = pk2(a.x, a.y); r.u[1] = pk2(a.z, a.w);
    r.u[2] = pk2(b.x, b.y); r.u[3] = pk2(b.z, b.w);
    return r.v;
}

// ---------------------------------------------------------------------------
// Kernel 1: fused transpose + theta/phi/g 1x1 conv via MFMA.  [frozen r14]
// ---------------------------------------------------------------------------
__global__ __launch_bounds__(256, 4) void k1_qkv(
    const float* __restrict__ x,
    const float* __restrict__ tw, const float* __restrict__ tbv,
    const float* __restrict__ pw, const float* __restrict__ pbv,
    const float* __restrict__ gw, const float* __restrict__ gbv,
    unsigned short* __restrict__ thetaT, unsigned short* __restrict__ phiT,
    unsigned short* __restrict__ g_dn)
{
    const int n0 = blockIdx.x * 64;
    const int kt = blockIdx.y;
    const int b  = blockIdx.z;
    const int tid = threadIdx.x;
    const float* W  = (kt==0) ? tw  : (kt==1) ? pw  : gw;
    const float* Bv = (kt==0) ? tbv : (kt==1) ? pbv : gbv;
    const float wsc = (kt==0) ? 1.4426950408889634f : 1.0f;   // log2(e)

    const int wq   = tid >> 6;
    const int lane = tid & 63;
    const int lr   = lane & 15;
    const int lg   = lane >> 4;

    __shared__ __align__(16) unsigned short T[64*72];  // x tile [k][n] bf16
    __shared__ __align__(16) short Wt[64*72];          // W tile [m][k] bf16
    __shared__ __align__(16) short Xt[64*72];          // x tile [n][k] bf16

    f32x4 acc[4];
    #pragma unroll
    for (int jt=0;jt<4;++jt) acc[jt] = (f32x4){0.f,0.f,0.f,0.f};

    const int srow = tid >> 2;           // staging row 0..63
    const int skq  = (tid & 3) * 16;     // staging 16-seg

    for (int k0 = 0; k0 < CIN; k0 += 64) {
        __syncthreads();                 // protect T/Wt/Xt prev-iter reads
        {   // stage W [64 m][64 k] fp32 -> bf16 (scaled)
            const float* wp = W + (size_t)srow*CIN + k0 + skq;
            float4 w0 = *reinterpret_cast<const float4*>(wp);
            float4 w1 = *reinterpret_cast<const float4*>(wp + 4);
            float4 w2 = *reinterpret_cast<const float4*>(wp + 8);
            float4 w3 = *reinterpret_cast<const float4*>(wp + 12);
            w0.x*=wsc; w0.y*=wsc; w0.z*=wsc; w0.w*=wsc;
            w1.x*=wsc; w1.y*=wsc; w1.z*=wsc; w1.w*=wsc;
            w2.x*=wsc; w2.y*=wsc; w2.z*=wsc; w2.w*=wsc;
            w3.x*=wsc; w3.y*=wsc; w3.z*=wsc; w3.w*=wsc;
            *reinterpret_cast<bf16x8*>(&Wt[srow*72 + skq])     = cvt8(w0, w1);
            *reinterpret_cast<bf16x8*>(&Wt[srow*72 + skq + 8]) = cvt8(w2, w3);
            // stage x [64 k][64 n] fp32 coalesced -> T bf16 [k][n]
            const float* xp = x + ((size_t)b*CIN + k0 + srow)*NPIX + n0 + skq;
            float4 a0 = *reinterpret_cast<const float4*>(xp);
            float4 a1 = *reinterpret_cast<const float4*>(xp + 4);
            float4 a2 = *reinterpret_cast<const float4*>(xp + 8);
            float4 a3 = *reinterpret_cast<const float4*>(xp + 12);
            *reinterpret_cast<bf16x8*>(&T[srow*72 + skq])     = cvt8(a0, a1);
            *reinterpret_cast<bf16x8*>(&T[srow*72 + skq + 8]) = cvt8(a2, a3);
        }
        __syncthreads();
        {   // transpose T[k][n] -> Xt[n][k]
            unsigned short v[16];
            #pragma unroll
            for (int i=0;i<16;++i) v[i] = T[(skq+i)*72 + srow];
            *reinterpret_cast<bf16x8*>(&Xt[srow*72 + skq])     = *reinterpret_cast<bf16x8*>(&v[0]);
            *reinterpret_cast<bf16x8*>(&Xt[srow*72 + skq + 8]) = *reinterpret_cast<bf16x8*>(&v[8]);
        }
        __syncthreads();

        __builtin_amdgcn_s_setprio(1);
        #pragma unroll
        for (int dc=0;dc<2;++dc){
            bf16x8 af = *reinterpret_cast<const bf16x8*>(&Wt[(wq*16+lr)*72 + dc*32 + lg*8]);
            #pragma unroll
            for (int jt=0;jt<4;++jt){
                bf16x8 bf = *reinterpret_cast<const bf16x8*>(&Xt[(jt*16+lr)*72 + dc*32 + lg*8]);
                acc[jt] = __builtin_amdgcn_mfma_f32_16x16x32_bf16(af, bf, acc[jt], 0,0,0);
            }
        }
        __builtin_amdgcn_s_setprio(0);
    }

    // acc[jt][r] = out[m = wq*16+lg*4+r][n = n0+jt*16+lr]
    const int mb = wq*16 + lg*4;
    float bv[4];
    #pragma unroll
    for (int r=0;r<4;++r) bv[r] = Bv[mb+r] * wsc;

    if (kt < 2){
        unsigned short* dst = (kt==0) ? thetaT : phiT;   // [b][n][d], d contig
        #pragma unroll
        for (int jt=0;jt<4;++jt){
            union { unsigned u[2]; u16x4 v; } o;
            o.u[0] = pk2(acc[jt][0]+bv[0], acc[jt][1]+bv[1]);
            o.u[1] = pk2(acc[jt][2]+bv[2], acc[jt][3]+bv[3]);
            *reinterpret_cast<u16x4*>(&dst[((size_t)b*NPIX + n0 + jt*16+lr)*DD + mb]) = o.v;
        }
    } else {
        #pragma unroll
        for (int jt=0;jt<4;++jt)
            #pragma unroll
            for (int r=0;r<4;++r)
                g_dn[((size_t)b*DD + mb+r)*NPIX + n0 + jt*16+lr] = f2bf(acc[jt][r]+bv[r]);
    }
}

// ---------------------------------------------------------------------------
// Kernel 2: MFMA flash attention.  [r16-structure, permanently frozen]
// + T1 XCD-AWARE BLOCK SWIZZLE: remap flat block id so the 32 q-blocks
// sharing one (ch,b) K/G chunk all land on ONE XCD (4 chunks = 4MB = L2).
// grid 1024 flat blocks (= 32 qt x NCHUNK x 4 b), block 256 (4 waves).
// ---------------------------------------------------------------------------
__global__ __launch_bounds__(256, 4) void k2_attn(
    const unsigned short* __restrict__ thetaT,
    const unsigned short* __restrict__ phiT,
    const unsigned short* __restrict__ g_dn,
    unsigned short* __restrict__ pY, float* __restrict__ pL)
{
    // --- bijective XCD swizzle: 1024 blocks = 8 XCDs x 128 slots ---
    const int flat = blockIdx.x;
    const int xcd  = flat & 7;
    const int idx  = flat >> 3;            // 0..127 within XCD
    const int grp  = (xcd << 2) + (idx >> 5);   // 0..31 -> (ch,b) group
    const int i0   = (idx & 31) * 128;     // q-tile within group
    const int ch   = grp & 7;
    const int b    = grp >> 3;

    const int tid  = threadIdx.x;
    const int wq   = tid >> 6;        // wave 0..3
    const int lane = tid & 63;
    const int lr   = lane & 15;       // row/col-in-16
    const int lg   = lane >> 4;       // k-group 0..3

    __shared__ __align__(16) short Kt[64*72];      // phiT tile [j][d] bf16 (pad 8)
    __shared__ __align__(16) short Gt[64*72];      // g tile [d][j] bf16 (pad 8)
    __shared__ __align__(16) short Pb[4*32*72];    // per-wave P [2 strips x 16 q][j]
    short* Pw = &Pb[wq*32*72];

    // Q fragments, strip0: rows i0+wq*16+lr ; strip1: +64
    bf16x8 qf0[2], qf1[2];
    {
        const unsigned short* qp0 = thetaT + ((size_t)b*NPIX + i0 + wq*16 + lr)*DD + lg*8;
        qf0[0] = *reinterpret_cast<const bf16x8*>(qp0);
        qf0[1] = *reinterpret_cast<const bf16x8*>(qp0 + 32);
        const unsigned short* qp1 = qp0 + (size_t)64*DD;
        qf1[0] = *reinterpret_cast<const bf16x8*>(qp1);
        qf1[1] = *reinterpret_cast<const bf16x8*>(qp1 + 32);
    }
    const bf16x8 onesf = { (short)0x3F80,(short)0x3F80,(short)0x3F80,(short)0x3F80,
                           (short)0x3F80,(short)0x3F80,(short)0x3F80,(short)0x3F80 };

    f32x4 yacc0[4], yacc1[4], lacc0, lacc1;
    #pragma unroll
    for (int dt=0;dt<4;++dt){
        yacc0[dt] = (f32x4){0.f,0.f,0.f,0.f};
        yacc1[dt] = (f32x4){0.f,0.f,0.f,0.f};
    }
    lacc0 = (f32x4){0.f,0.f,0.f,0.f};
    lacc1 = (f32x4){0.f,0.f,0.f,0.f};

    const unsigned short* phb = phiT + (size_t)b*NPIX*DD;
    const unsigned short* gb  = g_dn + (size_t)b*DD*NPIX;

    const int jbeg = ch * (NPIX / NCHUNK);
    const int jend = jbeg + (NPIX / NCHUNK);

    const int srow = tid >> 3;          // 0..31 (two row passes: +0, +32)
    const int scb  = (tid & 7) * 8;     // bf16 col seg

    for (int j0 = jbeg; j0 < jend; j0 += 64) {
        __syncthreads();                          // prev-tile reads of Kt/Gt done
        *reinterpret_cast<float4*>(&Kt[srow*72 + scb]) =
            *reinterpret_cast<const float4*>(&phb[(size_t)(j0+srow)*DD + scb]);
        *reinterpret_cast<float4*>(&Kt[(srow+32)*72 + scb]) =
            *reinterpret_cast<const float4*>(&phb[(size_t)(j0+srow+32)*DD + scb]);
        *reinterpret_cast<float4*>(&Gt[srow*72 + scb]) =
            *reinterpret_cast<const float4*>(&gb[(size_t)srow*NPIX + j0 + scb]);
        *reinterpret_cast<float4*>(&Gt[(srow+32)*72 + scb]) =
            *reinterpret_cast<const float4*>(&gb[(size_t)(srow+32)*NPIX + j0 + scb]);
        __syncthreads();

        // ---- S^T: mfma(A=K, B=Q).  Lane: q=lr (col), j = jt*16+lg*4+r ----
        f32x4 s0[4], s1[4];
        #pragma unroll
        for (int jt=0;jt<4;++jt){
            s0[jt] = (f32x4){0.f,0.f,0.f,0.f};
            s1[jt] = (f32x4){0.f,0.f,0.f,0.f};
        }
        __builtin_amdgcn_s_setprio(1);
        #pragma unroll
        for (int dc=0;dc<2;++dc){
            #pragma unroll
            for (int jt=0;jt<4;++jt){
                bf16x8 bf = *reinterpret_cast<const bf16x8*>(&Kt[(jt*16+lr)*72 + dc*32 + lg*8]);
                s0[jt] = __builtin_amdgcn_mfma_f32_16x16x32_bf16(bf, qf0[dc], s0[jt], 0,0,0);
                s1[jt] = __builtin_amdgcn_mfma_f32_16x16x32_bf16(bf, qf1[dc], s1[jt], 0,0,0);
            }
        }
        __builtin_amdgcn_s_setprio(0);

        // ---- p = exp2(S^T) -> packed bf16, one b64 write per (jt,strip) ----
        #pragma unroll
        for (int jt=0;jt<4;++jt){
            u32x2 w0, w1;
            w0.x = pk2(exp2f(s0[jt][0]), exp2f(s0[jt][1]));
            w0.y = pk2(exp2f(s0[jt][2]), exp2f(s0[jt][3]));
            *reinterpret_cast<u32x2*>(&Pw[lr*72      + jt*16 + lg*4]) = w0;
            w1.x = pk2(exp2f(s1[jt][0]), exp2f(s1[jt][1]));
            w1.y = pk2(exp2f(s1[jt][2]), exp2f(s1[jt][3]));
            *reinterpret_cast<u32x2*>(&Pw[(16+lr)*72 + jt*16 + lg*4]) = w1;
        }
        // same-wave write->read: compiler inserts lgkmcnt waits

        // ---- PV: each Gt fragment feeds both strips ----
        __builtin_amdgcn_s_setprio(1);
        #pragma unroll
        for (int jc=0;jc<2;++jc){
            bf16x8 af0 = *reinterpret_cast<const bf16x8*>(&Pw[lr*72      + jc*32 + lg*8]);
            bf16x8 af1 = *reinterpret_cast<const bf16x8*>(&Pw[(16+lr)*72 + jc*32 + lg*8]);
            #pragma unroll
            for (int dt=0;dt<4;++dt){
                bf16x8 gf = *reinterpret_cast<const bf16x8*>(&Gt[(dt*16+lr)*72 + jc*32 + lg*8]);
                yacc0[dt] = __builtin_amdgcn_mfma_f32_16x16x32_bf16(af0, gf, yacc0[dt], 0,0,0);
                yacc1[dt] = __builtin_amdgcn_mfma_f32_16x16x32_bf16(af1, gf, yacc1[dt], 0,0,0);
            }
            lacc0 = __builtin_amdgcn_mfma_f32_16x16x32_bf16(af0, onesf, lacc0, 0,0,0);
            lacc1 = __builtin_amdgcn_mfma_f32_16x16x32_bf16(af1, onesf, lacc1, 0,0,0);
        }
        __builtin_amdgcn_s_setprio(0);
    }

    // ---- epilogue: store UNNORMALIZED bf16 partials + l (both strips) ----
    {
        unsigned short* py0 = pY + (((size_t)b*NCHUNK + ch)*NPIX + i0 + wq*16)*DD;
        unsigned short* py1 = py0 + (size_t)64*DD;
        #pragma unroll
        for (int r=0;r<4;++r)
            #pragma unroll
            for (int dt=0;dt<4;++dt){
                py0[(size_t)(lg*4+r)*DD + dt*16 + lr] = f2bf(yacc0[dt][r]);
                py1[(size_t)(lg*4+r)*DD + dt*16 + lr] = f2bf(yacc1[dt][r]);
            }
        if (lr == 0){
            const size_t base = ((size_t)b*NCHUNK + ch)*NPIX + i0 + wq*16;
            #pragma unroll
            for (int r=0;r<4;++r){
                pL[base + lg*4+r]      = lacc0[r];
                pL[base + 64 + lg*4+r] = lacc1[r];
            }
        }
    }
}

// ---------------------------------------------------------------------------
// Kernel 3: FUSED combine + out conv via MFMA + BN partial stats. [r16]
// ---------------------------------------------------------------------------
__global__ __launch_bounds__(256) void k3_out(
    const unsigned short* __restrict__ pY, const float* __restrict__ pL,
    const float* __restrict__ ow, const float* __restrict__ ob,
    unsigned short* __restrict__ y2b,
    float* __restrict__ psum, float* __restrict__ qsum)
{
    const int n0 = blockIdx.x * 64;
    const int c0 = blockIdx.y * 64;
    const int b  = blockIdx.z;
    const int tid = threadIdx.x;
    const int wq   = tid >> 6;
    const int lane = tid & 63;
    const int lr   = lane & 15;
    const int lg   = lane >> 4;

    __shared__ __align__(16) short Ot[64*72];
    __shared__ __align__(16) short Yt[64*72];

    {   // stage ow [64 c][64 d] fp32 -> bf16
        const int srow = tid >> 2, skq = (tid & 3) * 16;
        const float* wp = ow + (size_t)(c0+srow)*DD + skq;
        float4 w0 = *reinterpret_cast<const float4*>(wp);
        float4 w1 = *reinterpret_cast<const float4*>(wp + 4);
        float4 w2 = *reinterpret_cast<const float4*>(wp + 8);
        float4 w3 = *reinterpret_cast<const float4*>(wp + 12);
        *reinterpret_cast<bf16x8*>(&Ot[srow*72 + skq])     = cvt8(w0, w1);
        *reinterpret_cast<bf16x8*>(&Ot[srow*72 + skq + 8]) = cvt8(w2, w3);

        // combine NCHUNK partials of yT[n=srow][d=skq..+15] in f32, normalize
        float ya[16];
        #pragma unroll
        for (int i=0;i<16;++i) ya[i] = 0.f;
        float lsum = 0.f;
        #pragma unroll
        for (int c=0;c<NCHUNK;++c){
            const unsigned short* yp =
                pY + (((size_t)b*NCHUNK + c)*NPIX + n0 + srow)*DD + skq;
            bf16x8 v0 = *reinterpret_cast<const bf16x8*>(yp);
            bf16x8 v1 = *reinterpret_cast<const bf16x8*>(yp + 8);
            #pragma unroll
            for (int i=0;i<8;++i){
                ya[i]   += bf2f((unsigned short)v0[i]);
                ya[8+i] += bf2f((unsigned short)v1[i]);
            }
            lsum += pL[((size_t)b*NCHUNK + c)*NPIX + n0 + srow];
        }
        const float inv = 1.f / lsum;
        union { unsigned u[8]; bf16x8 v[2]; } o;
        #pragma unroll
        for (int i=0;i<8;++i) o.u[i] = pk2(ya[2*i]*inv, ya[2*i+1]*inv);
        *reinterpret_cast<bf16x8*>(&Yt[srow*72 + skq])     = o.v[0];
        *reinterpret_cast<bf16x8*>(&Yt[srow*72 + skq + 8]) = o.v[1];
    }
    __syncthreads();

    f32x4 acc[4];
    #pragma unroll
    for (int jt=0;jt<4;++jt) acc[jt] = (f32x4){0.f,0.f,0.f,0.f};
    #pragma unroll
    for (int dc=0;dc<2;++dc){
        bf16x8 af = *reinterpret_cast<const bf16x8*>(&Ot[(wq*16+lr)*72 + dc*32 + lg*8]);
        #pragma unroll
        for (int jt=0;jt<4;++jt){
            bf16x8 bf = *reinterpret_cast<const bf16x8*>(&Yt[(jt*16+lr)*72 + dc*32 + lg*8]);
            acc[jt] = __builtin_amdgcn_mfma_f32_16x16x32_bf16(af, bf, acc[jt], 0,0,0);
        }
    }

    const int cb = c0 + wq*16 + lg*4;
    float bv[4];
    #pragma unroll
    for (int r=0;r<4;++r) bv[r] = ob[cb+r];

    float sr[4] = {0,0,0,0}, qr[4] = {0,0,0,0};
    #pragma unroll
    for (int jt=0;jt<4;++jt)
        #pragma unroll
        for (int r=0;r<4;++r){
            float v = acc[jt][r] + bv[r];
            y2b[((size_t)b*CIN + cb+r)*NPIX + n0 + jt*16+lr] = f2bf(v);
            sr[r] += v; qr[r] += v*v;
        }
    // reduce over lr (lane bits 0..3) -> per-channel partials for 64 n
    #pragma unroll
    for (int off=1; off<16; off<<=1)
        #pragma unroll
        for (int r=0;r<4;++r){
            sr[r] += __shfl_xor(sr[r], off);
            qr[r] += __shfl_xor(qr[r], off);
        }
    if (lr == 0){
        const int slot = b*64 + blockIdx.x;
        #pragma unroll
        for (int r=0;r<4;++r){
            psum[(size_t)(cb+r)*256 + slot] = sr[r];
            qsum[(size_t)(cb+r)*256 + slot] = qr[r];
        }
    }
}

// ---------------------------------------------------------------------------
// Kernel 3b: reduce [512][256] partials -> mean/inv (deterministic tree).
// ---------------------------------------------------------------------------
__global__ __launch_bounds__(256) void k3b_stats(
    const float* __restrict__ psum, const float* __restrict__ qsum,
    float* __restrict__ meanA, float* __restrict__ invA)
{
    const int c = blockIdx.x;
    const int tid = threadIdx.x;
    float s = psum[(size_t)c*256 + tid];
    float q = qsum[(size_t)c*256 + tid];
    __shared__ float rs[256], rq[256];
    rs[tid]=s; rq[tid]=q; __syncthreads();
    for (int off=128; off; off>>=1){
        if (tid<off){ rs[tid]+=rs[tid+off]; rq[tid]+=rq[tid+off]; }
        __syncthreads();
    }
    if (tid==0){
        const float n = (float)(BB*NPIX);
        float mm = rs[0] / n;
        float v = rq[0] / n - mm*mm;
        meanA[c]=mm; invA[c]=rsqrtf(v + 1e-5f);
    }
}

// ---------------------------------------------------------------------------
// Kernel 4: BN apply + residual.  Reads y2b (bf16, ws), writes out (f32).
// ---------------------------------------------------------------------------
__global__ __launch_bounds__(256) void k4_final(
    const float* __restrict__ x, const unsigned short* __restrict__ y2b,
    const float* __restrict__ meanA, const float* __restrict__ invA,
    const float* __restrict__ gamma, const float* __restrict__ beta,
    const float* __restrict__ scale, float* __restrict__ out)
{
    const float sc = scale[0];
    const int total4 = BB*CIN*NPIX/4;
    for (int i4 = blockIdx.x*blockDim.x + threadIdx.x; i4 < total4;
         i4 += gridDim.x*blockDim.x){
        int c = (i4 >> 10) & (CIN-1);
        float4 xv = reinterpret_cast<const float4*>(x)[i4];
        ushort4 yv = reinterpret_cast<const ushort4*>(y2b)[i4];
        float mm = meanA[c], iv = invA[c], g = gamma[c], bt = beta[c];
        float4 o;
        o.x = xv.x + sc*(g*(bf2f(yv.x)-mm)*iv + bt);
        o.y = xv.y + sc*(g*(bf2f(yv.y)-mm)*iv + bt);
        o.z = xv.z + sc*(g*(bf2f(yv.z)-mm)*iv + bt);
        o.w = xv.w + sc*(g*(bf2f(yv.w)-mm)*iv + bt);
        reinterpret_cast<float4*>(out)[i4] = o;
    }
}

// ---------------------------------------------------------------------------
extern "C" void kernel_launch(void* const* d_in, const int* in_sizes, int n_in,
                              void* d_out, int out_size, void* d_ws, size_t ws_size,
                              hipStream_t stream)
{
    const float* x     = (const float*)d_in[0];
    const float* tw    = (const float*)d_in[1];
    const float* tbv   = (const float*)d_in[2];
    const float* pw    = (const float*)d_in[3];
    const float* pbv   = (const float*)d_in[4];
    const float* gw    = (const float*)d_in[5];
    const float* gbv   = (const float*)d_in[6];
    const float* ow    = (const float*)d_in[7];
    const float* ob    = (const float*)d_in[8];
    const float* gamma = (const float*)d_in[9];
    const float* beta  = (const float*)d_in[10];
    const float* scale = (const float*)d_in[11];
    float* out = (float*)d_out;

    char* wsb = (char*)d_ws;
    unsigned short* thetaT = (unsigned short*)(wsb);             // 2 MB
    unsigned short* phiT   = (unsigned short*)(wsb + 2097152);   // 2 MB
    unsigned short* g_dn   = (unsigned short*)(wsb + 4194304);   // 2 MB
    float*          pL     = (float*)(wsb + 8388608);            // 512 KB
    float*          psum   = (float*)(wsb + 8912896);            // 512 KB
    float*          qsum   = (float*)(wsb + 9437184);            // 512 KB
    float*          meanA  = (float*)(wsb + 9961472);
    float*          invA   = (float*)(wsb + 9963520);
    unsigned short* y2b    = (unsigned short*)(wsb + 16777216);  // 16.8 MB

    // d_out (33.5 MB) time-shared scratch:
    //   phase B: pY [B][NCHUNK=8][N][D] bf16 (16.8 MB) -- k2 writes, k3 reads
    //   phase C: final output f32 -- k4 writes (every element)
    unsigned short* pY = (unsigned short*)d_out;

    k1_qkv <<<dim3(64,3,4), 256, 0, stream>>>(x, tw, tbv, pw, pbv, gw, gbv,
                                              thetaT, phiT, g_dn);
    k2_attn<<<1024, 256, 0, stream>>>(thetaT, phiT, g_dn, pY, pL);
    k3_out <<<dim3(64,8,4), 256, 0, stream>>>(pY, pL, ow, ob, y2b, psum, qsum);
    k3b_stats<<<512, 256, 0, stream>>>(psum, qsum, meanA, invA);
    k4_final<<<2048, 256, 0, stream>>>(x, y2b, meanA, invA, gamma, beta, scale, out);
}